// Round 6
// baseline (9766.798 us; speedup 1.0000x reference)
//
#include <hip/hip_runtime.h>

// Round 6: verbatim resubmission (rounds 3-5 all died in infra; kernel has run
// exactly once, round 2, diagnosed ws-guard trip -> fixed by 543->312 MB cut).
// Design: CSR-gather aggregation + fused dual-GEMM per relation, dst-grouped
// f32 accumulator, bf16 activation ping-pong, u16 CSR col. ws = 311.9 MB.
// Sentinel: ws guard trip -> out = -1 (absmax ~1.98).

typedef unsigned int  uint32;
typedef unsigned short u16;

#define NT 9
#define NN 50000
#define NE 800000
#define H  128

// relation tables (REL = [(0,1),(1,0),(0,2),(2,0),(1,2),(0,3),(3,0),(3,7),
//                         (0,4),(4,0),(0,8),(1,4),(0,6),(0,5),(5,0)])
static const int rel_src_h[15] = {0,1,0,2,1,0,3,3,0,4,0,1,0,0,5};
// relations grouped by dst type:
// d0:{r1,r3,r6,r9,r14} d1:{r0} d2:{r2,r4} d3:{r5} d4:{r8,r11} d5:{r13}
// d6:{r12} d7:{r7} d8:{r10}
static const int g_order[15] = {1,3,6,9,14, 0, 2,4, 5, 8,11, 13, 12, 7, 10};
static const int g_start[10] = {0,5,6,8,9,11,12,13,14,15};
static const float inv_cnt_h[NT] = {0.2f,1.f,0.5f,1.f,0.5f,1.f,1.f,1.f,1.f};

// ---- bf16 helpers (bit-exact, RNE for the store) ----
__device__ __forceinline__ float bf16lo(uint32 u) { return __uint_as_float(u << 16); }
__device__ __forceinline__ float bf16hi(uint32 u) { return __uint_as_float(u & 0xffff0000u); }
__device__ __forceinline__ u16 f2bf(float f) {
    uint32 u = __float_as_uint(f);
    u += 0x7fffu + ((u >> 16) & 1u);   // round to nearest even
    return (u16)(u >> 16);
}

// ---------------- CSR build ----------------
__global__ void hist_kernel(const int* __restrict__ edges, int* __restrict__ cnt) {
    int r = blockIdx.y;
    int e = blockIdx.x * blockDim.x + threadIdx.x;
    if (e < NE) {
        int dst = edges[(size_t)r * 2 * NE + NE + e];
        atomicAdd(&cnt[r * NN + dst], 1);
    }
}

// exclusive scan of cnt -> row_ptr; rewrites cnt in place as fill-cursor
__global__ void scan_kernel(int* __restrict__ cnt, int* __restrict__ row_ptr) {
    int r = blockIdx.x;
    __shared__ int sdata[1024];
    int carry = 0;
    for (int base = 0; base < NN; base += 1024) {
        int i = base + threadIdx.x;
        int v = (i < NN) ? cnt[r * NN + i] : 0;
        sdata[threadIdx.x] = v;
        __syncthreads();
        for (int off = 1; off < 1024; off <<= 1) {
            int t = (threadIdx.x >= off) ? sdata[threadIdx.x - off] : 0;
            __syncthreads();
            sdata[threadIdx.x] += t;
            __syncthreads();
        }
        int excl = sdata[threadIdx.x] - v;
        if (i < NN) {
            row_ptr[r * (NN + 1) + i] = carry + excl;
            cnt[r * NN + i] = carry + excl;
        }
        carry += sdata[1023];
        __syncthreads();
    }
    if (threadIdx.x == 0) row_ptr[r * (NN + 1) + NN] = carry;
}

__global__ void fill_kernel(const int* __restrict__ edges, int* __restrict__ cursor,
                            u16* __restrict__ col) {
    int r = blockIdx.y;
    int e = blockIdx.x * blockDim.x + threadIdx.x;
    if (e < NE) {
        int src = edges[(size_t)r * 2 * NE + e];
        int dst = edges[(size_t)r * 2 * NE + NE + e];
        int pos = atomicAdd(&cursor[r * NN + dst], 1);
        col[(size_t)r * NE + pos] = (u16)src;
    }
}

// ---------------- scatter-mean via CSR gather ----------------
// layer 0: f32 input, D=64; one wave per dst row
__global__ __launch_bounds__(256) void agg64_kernel(const float* __restrict__ X,
                                                    const int* __restrict__ row_ptr,
                                                    const u16* __restrict__ col,
                                                    float* __restrict__ msg) {
    int wave = threadIdx.x >> 6, lane = threadIdx.x & 63;
    int row = blockIdx.x * 4 + wave;
    if (row >= NN) return;
    int beg = row_ptr[row], end = row_ptr[row + 1];
    float acc = 0.f;
    for (int i = beg; i < end; ++i)
        acc += X[(size_t)col[i] * 64 + lane];
    msg[(size_t)row * 64 + lane] = acc / fmaxf((float)(end - beg), 1.0f);
}

// layers 1-2: bf16 input, D=128 (each lane: 2 elems via one dword)
__global__ __launch_bounds__(256) void agg128b_kernel(const u16* __restrict__ X,
                                                      const int* __restrict__ row_ptr,
                                                      const u16* __restrict__ col,
                                                      float* __restrict__ msg) {
    int wave = threadIdx.x >> 6, lane = threadIdx.x & 63;
    int row = blockIdx.x * 4 + wave;
    if (row >= NN) return;
    int beg = row_ptr[row], end = row_ptr[row + 1];
    float acc0 = 0.f, acc1 = 0.f;
    for (int i = beg; i < end; ++i) {
        const uint32* src = (const uint32*)(X + (size_t)col[i] * 128);
        uint32 u = src[lane];
        acc0 += bf16lo(u);
        acc1 += bf16hi(u);
    }
    float inv = 1.0f / fmaxf((float)(end - beg), 1.0f);
    float2 o = {acc0 * inv, acc1 * inv};
    *reinterpret_cast<float2*>(msg + (size_t)row * 128 + lane * 2) = o;
}

// ---------------- fused dual GEMM: acc (+)= msg@Wl + Xd@Wr + bias ----------------
// block 256, M-tile 64, N=128 full, K chunked by 32. Amsg f32 stride K;
// Ax f32 (AXBF=false) or bf16 (AXBF=true) stride K.
template <int K, bool AXBF, bool FIRST>
__global__ __launch_bounds__(256) void gemm_kernel(const float* __restrict__ Amsg,
                                                   const void* __restrict__ Ax,
                                                   const float* __restrict__ Bl,
                                                   const float* __restrict__ Br,
                                                   const float* __restrict__ bias,
                                                   float* __restrict__ Out) {
    __shared__ float As[2][32][64];   // [msg/x][k][m]
    __shared__ float Bs[2][32][H];    // [l/r][k][h]
    int t = threadIdx.x;
    int tx = t & 31;   // cols 4*tx..4*tx+3
    int ty = t >> 5;   // rows 8*ty..8*ty+7
    int m0 = blockIdx.x * 64;
    float acc[8][4] = {};

    for (int kc = 0; kc < K; kc += 32) {
        // stage A (both operands), transposed [k][m]
        {
            int arow = t >> 3;            // 0..31
            int kq = (t & 7) * 4;         // 0,4,...,28
            #pragma unroll
            for (int half = 0; half < 2; ++half) {
                int m = arow + half * 32;
                int gm = m0 + m;
                float4 va = {0, 0, 0, 0}, vb = {0, 0, 0, 0};
                if (gm < NN) {
                    va = *reinterpret_cast<const float4*>(Amsg + (size_t)gm * K + kc + kq);
                    if (!AXBF) {
                        vb = *reinterpret_cast<const float4*>((const float*)Ax + (size_t)gm * K + kc + kq);
                    } else {
                        const u16* axp = (const u16*)Ax + (size_t)gm * K + kc + kq;
                        uint2 ub = *reinterpret_cast<const uint2*>(axp);
                        vb.x = bf16lo(ub.x); vb.y = bf16hi(ub.x);
                        vb.z = bf16lo(ub.y); vb.w = bf16hi(ub.y);
                    }
                }
                As[0][kq + 0][m] = va.x; As[0][kq + 1][m] = va.y;
                As[0][kq + 2][m] = va.z; As[0][kq + 3][m] = va.w;
                As[1][kq + 0][m] = vb.x; As[1][kq + 1][m] = vb.y;
                As[1][kq + 2][m] = vb.z; As[1][kq + 3][m] = vb.w;
            }
        }
        // stage B: 32x128 each
        {
            #pragma unroll
            for (int i = 0; i < 4; ++i) {
                int idx = t + i * 256;
                int k = idx >> 5;
                int h4 = (idx & 31) * 4;
                *reinterpret_cast<float4*>(&Bs[0][k][h4]) =
                    *reinterpret_cast<const float4*>(Bl + (size_t)(kc + k) * H + h4);
                *reinterpret_cast<float4*>(&Bs[1][k][h4]) =
                    *reinterpret_cast<const float4*>(Br + (size_t)(kc + k) * H + h4);
            }
        }
        __syncthreads();
        #pragma unroll
        for (int k = 0; k < 32; ++k) {
            float4 a0 = *reinterpret_cast<const float4*>(&As[0][k][ty * 8]);
            float4 a1 = *reinterpret_cast<const float4*>(&As[0][k][ty * 8 + 4]);
            float4 c0 = *reinterpret_cast<const float4*>(&As[1][k][ty * 8]);
            float4 c1 = *reinterpret_cast<const float4*>(&As[1][k][ty * 8 + 4]);
            float4 b0 = *reinterpret_cast<const float4*>(&Bs[0][k][tx * 4]);
            float4 d0 = *reinterpret_cast<const float4*>(&Bs[1][k][tx * 4]);
            float am[8] = {a0.x, a0.y, a0.z, a0.w, a1.x, a1.y, a1.z, a1.w};
            float ax[8] = {c0.x, c0.y, c0.z, c0.w, c1.x, c1.y, c1.z, c1.w};
            float bl[4] = {b0.x, b0.y, b0.z, b0.w};
            float br[4] = {d0.x, d0.y, d0.z, d0.w};
            #pragma unroll
            for (int i = 0; i < 8; ++i)
                #pragma unroll
                for (int j = 0; j < 4; ++j)
                    acc[i][j] += am[i] * bl[j] + ax[i] * br[j];
        }
        __syncthreads();
    }

    float4 bv = *reinterpret_cast<const float4*>(bias + tx * 4);
    #pragma unroll
    for (int i = 0; i < 8; ++i) {
        int row = m0 + ty * 8 + i;
        if (row < NN) {
            float* o = Out + (size_t)row * H + tx * 4;
            float4 v = {acc[i][0] + bv.x, acc[i][1] + bv.y, acc[i][2] + bv.z, acc[i][3] + bv.w};
            if (!FIRST) {
                float4 old = *reinterpret_cast<const float4*>(o);
                v.x += old.x; v.y += old.y; v.z += old.z; v.w += old.w;
            }
            *reinterpret_cast<float4*>(o) = v;
        }
    }
}

// ---------------- x*inv_cnt, leaky relu, layernorm -> bf16 ----------------
__global__ __launch_bounds__(256) void actnorm_kernel(const float* __restrict__ In,
                                                      u16* __restrict__ Outp,
                                                      const float* __restrict__ g,
                                                      const float* __restrict__ be,
                                                      float inv_cnt) {
    int wave = threadIdx.x >> 6, lane = threadIdx.x & 63;
    int row = blockIdx.x * 4 + wave;
    if (row >= NN) return;
    float2 v = *reinterpret_cast<const float2*>(In + (size_t)row * H + lane * 2);
    v.x *= inv_cnt; v.y *= inv_cnt;
    v.x = v.x >= 0.f ? v.x : 0.01f * v.x;
    v.y = v.y >= 0.f ? v.y : 0.01f * v.y;
    float s = v.x + v.y;
    #pragma unroll
    for (int off = 32; off > 0; off >>= 1) s += __shfl_xor(s, off);
    float mu = s * (1.0f / 128.0f);
    float dx = v.x - mu, dy = v.y - mu;
    float q = dx * dx + dy * dy;
    #pragma unroll
    for (int off = 32; off > 0; off >>= 1) q += __shfl_xor(q, off);
    float rstd = rsqrtf(q * (1.0f / 128.0f) + 1e-5f);
    float ox = dx * rstd * g[lane * 2] + be[lane * 2];
    float oy = dy * rstd * g[lane * 2 + 1] + be[lane * 2 + 1];
    uint32 packed = (uint32)f2bf(ox) | ((uint32)f2bf(oy) << 16);
    *reinterpret_cast<uint32*>(Outp + (size_t)row * H + lane * 2) = packed;
}

// ---------------- final FC + sigmoid ----------------
__global__ __launch_bounds__(256) void final_kernel(const u16* __restrict__ X,
                                                    const float* __restrict__ Wfc,
                                                    const float* __restrict__ bfc,
                                                    float* __restrict__ out) {
    int wave = threadIdx.x >> 6, lane = threadIdx.x & 63;
    int n = blockIdx.x * 4 + wave;
    if (n >= NN) return;
    float s = 0.f;
    #pragma unroll
    for (int tpe = 0; tpe < NT; ++tpe) {
        uint32 u = *reinterpret_cast<const uint32*>(X + ((size_t)tpe * NN + n) * H + lane * 2);
        float2 w = *reinterpret_cast<const float2*>(Wfc + tpe * H + lane * 2);
        s += bf16lo(u) * w.x + bf16hi(u) * w.y;
    }
    #pragma unroll
    for (int off = 32; off > 0; off >>= 1) s += __shfl_xor(s, off);
    if (lane == 0) out[n] = 1.0f / (1.0f + expf(-(s + bfc[0])));
}

// sentinel: ws too small -> fill out with -1 (distinguishable from all-zero)
__global__ void fail_fill(float* out, int n) {
    int i = blockIdx.x * 256 + threadIdx.x;
    if (i < n) out[i] = -1.0f;
}

// ---------------- host ----------------
extern "C" void kernel_launch(void* const* d_in, const int* in_sizes, int n_in,
                              void* d_out, int out_size, void* d_ws, size_t ws_size,
                              hipStream_t stream) {
    const float* x = (const float*)d_in[0];
    const int* edges = (const int*)d_in[1];
    const float* Wl[3] = {(const float*)d_in[2], (const float*)d_in[5], (const float*)d_in[8]};
    const float* Wr[3] = {(const float*)d_in[3], (const float*)d_in[6], (const float*)d_in[9]};
    const float* bb[3] = {(const float*)d_in[4], (const float*)d_in[7], (const float*)d_in[10]};
    const float* g[3] = {(const float*)d_in[11], (const float*)d_in[13], (const float*)d_in[15]};
    const float* be[3] = {(const float*)d_in[12], (const float*)d_in[14], (const float*)d_in[16]};
    const float* Wfc = (const float*)d_in[17];
    const float* bfc = (const float*)d_in[18];
    float* out = (float*)d_out;

    char* p = (char*)d_ws;
    auto alloc = [&](size_t bytes) {
        void* q = (void*)p;
        p += (bytes + 255) & ~(size_t)255;
        return q;
    };
    u16* Xb0 = (u16*)alloc((size_t)NT * NN * H * 2);       // 115.2 MB
    u16* Xb1 = (u16*)alloc((size_t)NT * NN * H * 2);       // 115.2 MB
    float* accf = (float*)alloc((size_t)NN * H * 4);       // 25.6 MB
    float* msg = (float*)alloc((size_t)NN * H * 4);        // 25.6 MB
    int* row_ptr = (int*)alloc((size_t)15 * (NN + 1) * 4); // 3.0 MB
    int* cnt = (int*)alloc((size_t)15 * NN * 4);           // 3.0 MB (also cursor)
    u16* col = (u16*)alloc((size_t)15 * NE * 2);           // 24.0 MB
    if ((size_t)(p - (char*)d_ws) > ws_size) {
        fail_fill<<<(NN + 255) / 256, 256, 0, stream>>>(out, NN);
        return;
    }

    // CSR build (rebuilt each call; d_ws is re-poisoned between calls)
    hipMemsetAsync(cnt, 0, sizeof(int) * 15 * NN, stream);
    hist_kernel<<<dim3((NE + 255) / 256, 15), 256, 0, stream>>>(edges, cnt);
    scan_kernel<<<15, 1024, 0, stream>>>(cnt, row_ptr);
    fill_kernel<<<dim3((NE + 255) / 256, 15), 256, 0, stream>>>(edges, cnt, col);

    const int agg_grid = (NN + 3) / 4;      // 12500
    const int gemm_grid = (NN + 63) / 64;   // 782

    for (int layer = 0; layer < 3; ++layer) {
        const u16* Xin16 = (layer == 1) ? Xb0 : Xb1;   // layer 0 unused
        u16* Xout16 = (layer == 1) ? Xb1 : Xb0;        // L0->Xb0, L1->Xb1, L2->Xb0
        const int Din = layer ? H : 64;
        for (int grp = 0; grp < NT; ++grp) {
            int d = grp;
            bool first = true;
            for (int oi = g_start[grp]; oi < g_start[grp + 1]; ++oi) {
                int r = g_order[oi];
                int s = rel_src_h[r];
                const int* rp = row_ptr + r * (NN + 1);
                const u16* cl = col + (size_t)r * NE;
                const float* wl = Wl[layer] + (size_t)r * Din * H;
                const float* wr = Wr[layer] + (size_t)r * Din * H;
                const float* bi = bb[layer] + r * H;
                if (layer == 0) {
                    agg64_kernel<<<agg_grid, 256, 0, stream>>>(x + (size_t)s * NN * 64, rp, cl, msg);
                    if (first)
                        gemm_kernel<64, false, true><<<gemm_grid, 256, 0, stream>>>(
                            msg, x + (size_t)d * NN * 64, wl, wr, bi, accf);
                    else
                        gemm_kernel<64, false, false><<<gemm_grid, 256, 0, stream>>>(
                            msg, x + (size_t)d * NN * 64, wl, wr, bi, accf);
                } else {
                    agg128b_kernel<<<agg_grid, 256, 0, stream>>>(Xin16 + (size_t)s * NN * H, rp, cl, msg);
                    if (first)
                        gemm_kernel<128, true, true><<<gemm_grid, 256, 0, stream>>>(
                            msg, Xin16 + (size_t)d * NN * H, wl, wr, bi, accf);
                    else
                        gemm_kernel<128, true, false><<<gemm_grid, 256, 0, stream>>>(
                            msg, Xin16 + (size_t)d * NN * H, wl, wr, bi, accf);
                }
                first = false;
            }
            actnorm_kernel<<<agg_grid, 256, 0, stream>>>(accf, Xout16 + (size_t)d * NN * H,
                                                         g[layer], be[layer], inv_cnt_h[grp]);
        }
    }
    final_kernel<<<agg_grid, 256, 0, stream>>>(Xb0, Wfc, bfc, out);
}